// Round 1
// 13743.054 us; speedup vs baseline: 1.2252x; 1.2252x over previous
//
#include <hip/hip_runtime.h>
#include <cstdint>
#include <cstddef>

#define B_    64
#define T_    1024
#define D_    256
#define H_    512
#define BU_   512
#define GRID_ 256
#define NT_   512
// 8 independent batch groups; group g = blocks with blockIdx%8==g (XCD co-located
// under round-robin dispatch — heuristic only, protocol stays agent-scope/L3).
// Each group: 32 blocks x (8 rows, 16 cols); per wave: 8 rows x 2 cols.

__device__ __forceinline__ float fsigmoid(float x) { return 1.f / (1.f + __expf(-x)); }
__device__ __forceinline__ float ftanh(float x)    { return 2.f / (1.f + __expf(-2.f * x)) - 1.f; }

// Relaxed agent-scope atomic store: sc0/sc1 write-through, visible at L3 once
// vmcnt-drained, never dirty in any L2.
__device__ __forceinline__ void astore(float* p, float v) {
  union { float f; unsigned u; } c; c.f = v;
  __hip_atomic_store((unsigned*)p, c.u, __ATOMIC_RELAXED, __HIP_MEMORY_SCOPE_AGENT);
}

// Fence-free group barrier over 32 blocks: 4 leaves x 8 -> root(4) -> gen.
// Same proven ordering argument as the 256-wide version:
//   producer: sc0sc1 data stores -> s_waitcnt(0) (data at L3) -> leaf RMW.
//   leaf-last's RMW observed => its leaf's 8 producers committed; chain through
//   root RMW -> gen store is HW-ordered (same thread, vmcnt retires in order).
// Consumer: poll gen (L3), then ONE buffer_inv sc1 (clean stale bb/h lines out
// of L1/L2; no dirty exchange data exists), then cached loads see fresh data.
__device__ __forceinline__ void group_barrier(unsigned* gbar) {
  __syncthreads();
  if (threadIdx.x == 0) {
    const int glb = (int)(blockIdx.x >> 3);              // 0..31 within group
    unsigned* leaf = gbar + ((glb >> 3) << 6);           // 4 leaves, 256 B apart
    unsigned* root = gbar + 256;                         // byte 1024
    unsigned* gen  = gbar + 320;                         // byte 1280
    unsigned g = __hip_atomic_load(gen, __ATOMIC_RELAXED, __HIP_MEMORY_SCOPE_AGENT);
    __builtin_amdgcn_s_waitcnt(0);  // drain my sc0sc1 data stores to L3
    asm volatile("" ::: "memory");
    unsigned a = __hip_atomic_fetch_add(leaf, 1u, __ATOMIC_RELAXED, __HIP_MEMORY_SCOPE_AGENT);
    bool done = false;
    if (a == 7u) {
      __hip_atomic_store(leaf, 0u, __ATOMIC_RELAXED, __HIP_MEMORY_SCOPE_AGENT);
      unsigned b = __hip_atomic_fetch_add(root, 1u, __ATOMIC_RELAXED, __HIP_MEMORY_SCOPE_AGENT);
      if (b == 3u) {
        __hip_atomic_store(root, 0u, __ATOMIC_RELAXED, __HIP_MEMORY_SCOPE_AGENT);
        __hip_atomic_store(gen, g + 1u, __ATOMIC_RELAXED, __HIP_MEMORY_SCOPE_AGENT);
        done = true;
      }
    }
    if (!done) {
      while (__hip_atomic_load(gen, __ATOMIC_RELAXED, __HIP_MEMORY_SCOPE_AGENT) == g)
        __builtin_amdgcn_s_sleep(1);
    }
    // invalidate stale clean lines (L1+L2); dirty (out) lines are preserved.
    asm volatile("buffer_inv sc1\n\ts_waitcnt vmcnt(0)" ::: "memory");
  }
  __syncthreads();
}

__global__ __launch_bounds__(NT_, 2) void cfc_kernel(
    const float* __restrict__ x,    const float* __restrict__ ts,
    const float* __restrict__ h0,   const float* __restrict__ s0,
    const float* __restrict__ Wbb,  const float* __restrict__ bbb,
    const float* __restrict__ Wff1, const float* __restrict__ bff1,
    const float* __restrict__ Wff2, const float* __restrict__ bff2,
    const float* __restrict__ Wta,  const float* __restrict__ bta,
    const float* __restrict__ Wtb,  const float* __restrict__ btb,
    float* __restrict__ out, float* __restrict__ hws,
    float* __restrict__ bbws, unsigned* __restrict__ bar)
{
  __shared__ float part[8][16][66];   // 33792 B, stride 66 -> conflict-free
  __shared__ float sums[8][64];       //  2048 B
  __shared__ float sts[8][1028];      // 32896 B: group's ts rows, staged once

  const int tid  = threadIdx.x;
  const int wv   = tid >> 6;
  const int lane = tid & 63;
  const int g    = (int)(blockIdx.x & 7);   // group id (≈ XCD id)
  const int glb  = (int)(blockIdx.x >> 3);  // 0..31 within group
  const int g8   = g * 8;                   // first batch row of this group
  const int col0 = glb * 16 + wv * 2;       // this wave's 2 output columns

  unsigned* gbar = bar + (g << 9);          // 2 KB barrier region per group

  // ---- weights into registers (one-time; k = i*256 + lane*4 + e)
  float w1[2][3][4];
  #pragma unroll
  for (int c = 0; c < 2; ++c)
    #pragma unroll
    for (int i = 0; i < 3; ++i)
      #pragma unroll
      for (int e = 0; e < 4; ++e)
        w1[c][i][e] = Wbb[(size_t)(i * 256 + lane * 4 + e) * BU_ + (col0 + c)];

  float w2[4][2][2][4];
  const float* Wm[4] = {Wff1, Wff2, Wta, Wtb};
  #pragma unroll
  for (int m = 0; m < 4; ++m)
    #pragma unroll
    for (int c = 0; c < 2; ++c)
      #pragma unroll
      for (int i = 0; i < 2; ++i)
        #pragma unroll
        for (int e = 0; e < 4; ++e)
          w2[m][c][i][e] = Wm[m][(size_t)(i * 256 + lane * 4 + e) * H_ + (col0 + c)];

  float bb_b[2], fb1[2], fb2[2], fba[2], fbb2[2];
  #pragma unroll
  for (int c = 0; c < 2; ++c) {
    bb_b[c] = bbb[col0 + c];
    fb1[c]  = bff1[col0 + c];
    fb2[c]  = bff2[col0 + c];
    fba[c]  = bta[col0 + c];
    fbb2[c] = btb[col0 + c];
  }

  // s state lives in a register of lanes 0..15 (row rl=lane>>1, col c=lane&1)
  float sv = 0.f;
  if (lane < 16)
    sv = s0[(size_t)(g8 + (lane >> 1)) * H_ + col0 + (lane & 1)];

  // stage this group's ts rows into LDS (read every step, never changes)
  for (int i = tid; i < 8 * 1024; i += NT_)
    sts[i >> 10][i & 1023] = ts[(size_t)(g8 + (i >> 10)) * T_ + (i & 1023)];

  // init hws rows of this group (blocks glb<8 each own one row)
  if (glb < 8) {
    const int row = g8 + glb;
    astore(hws + (size_t)row * H_ + tid, h0[(size_t)row * H_ + tid]);
  }
  group_barrier(gbar);

  for (int t = 0; t < T_; ++t) {
    // ============ Phase 1: bb[g-rows, col0..+1] = silu(z @ Wbb + bbb) =======
    float p[16];
    #pragma unroll
    for (int o = 0; o < 16; ++o) p[o] = 0.f;

    #pragma unroll
    for (int r = 0; r < 8; ++r) {
      const int row = g8 + r;
      const float4 zx  = ((const float4*)(x + ((size_t)row * T_ + t) * D_))[lane];
      const float4* hrow = (const float4*)(hws + (size_t)row * H_);
      const float4 zh0 = hrow[lane];
      const float4 zh1 = hrow[lane + 64];
      // Deferred coalesced out-write: group-local block r owns out row g8+r;
      // wave 0 already holds h(t-1)[row][:] spread across lanes.
      if (t > 0 && r == glb && wv == 0) {
        float4* op = (float4*)(out + ((size_t)row * T_ + (t - 1)) * H_);
        op[lane]      = zh0;
        op[lane + 64] = zh1;
      }
      #pragma unroll
      for (int c = 0; c < 2; ++c) {
        float a;
        a  = zx.x  * w1[c][0][0]; a += zx.y  * w1[c][0][1];
        a += zx.z  * w1[c][0][2]; a += zx.w  * w1[c][0][3];
        a += zh0.x * w1[c][1][0]; a += zh0.y * w1[c][1][1];
        a += zh0.z * w1[c][1][2]; a += zh0.w * w1[c][1][3];
        a += zh1.x * w1[c][2][0]; a += zh1.y * w1[c][2][1];
        a += zh1.z * w1[c][2][2]; a += zh1.w * w1[c][2][3];
        p[r * 2 + c] = a;
      }
    }

    #pragma unroll
    for (int o = 0; o < 16; ++o) part[wv][o][lane] = p[o];
    if (lane < 16) {
      const float2* pp = (const float2*)(&part[wv][lane][0]);
      float se = 0.f, so = 0.f;
      #pragma unroll
      for (int i = 0; i < 32; ++i) { float2 v = pp[i]; se += v.x; so += v.y; }
      const float pre = se + so + bb_b[lane & 1];
      const float bbv = pre * fsigmoid(pre);
      const int row = g8 + (lane >> 1);
      astore(bbws + (size_t)row * BU_ + col0 + (lane & 1), bbv);
    }
    group_barrier(gbar);  // group's bb at L3, caches invalidated

    // ============ Phase 2: four mats + recurrence ============
    #pragma unroll
    for (int b = 0; b < 4; ++b) {
      float q[16];
      #pragma unroll
      for (int o = 0; o < 16; ++o) q[o] = 0.f;
      #pragma unroll
      for (int rr = 0; rr < 2; ++rr) {
        const int row = g8 + b * 2 + rr;
        const float4* brow = (const float4*)(bbws + (size_t)row * BU_);
        const float4 v0 = brow[lane];
        const float4 v1 = brow[lane + 64];
        #pragma unroll
        for (int c = 0; c < 2; ++c)
          #pragma unroll
          for (int m = 0; m < 4; ++m) {
            float a;
            a  = v0.x * w2[m][c][0][0]; a += v0.y * w2[m][c][0][1];
            a += v0.z * w2[m][c][0][2]; a += v0.w * w2[m][c][0][3];
            a += v1.x * w2[m][c][1][0]; a += v1.y * w2[m][c][1][1];
            a += v1.z * w2[m][c][1][2]; a += v1.w * w2[m][c][1][3];
            q[rr * 8 + c * 4 + m] = a;
          }
      }
      #pragma unroll
      for (int o = 0; o < 16; ++o) part[wv][o][lane] = q[o];
      if (lane < 16) {
        const float2* pp = (const float2*)(&part[wv][lane][0]);
        float se = 0.f, so = 0.f;
        #pragma unroll
        for (int i = 0; i < 32; ++i) { float2 v = pp[i]; se += v.x; so += v.y; }
        sums[wv][b * 16 + lane] = se + so;
      }
    }

    if (lane < 16) {
      const int rl = lane >> 1, c = lane & 1;
      const int row = g8 + rl;
      const float4 Sm = *(const float4*)&sums[wv][(rl >> 1) * 16 + (rl & 1) * 8 + c * 4];
      const float tsv = sts[rl][t];
      const float tsn = 1.f / tsv;
      const float wts = __expf(tsn * (1.f - 2.f * __logf(tsn)));
      const float f1  = ftanh(Sm.x + fb1[c]);
      const float f2  = ftanh(Sm.y + fb2[c]);
      const float tav = Sm.z + fba[c];
      const float tbv = Sm.w + fbb2[c];
      sv += tav * wts + tbv;
      const float ti = fsigmoid(sv);
      const float hn = f1 + ti * (f2 - f1);
      astore(hws + (size_t)row * H_ + col0 + c, hn);
    }
    group_barrier(gbar);  // group's h at L3, caches invalidated
  }

  // Tail: out[row, T-1, :] = h(T-1)[row] for this group's rows
  if (glb < 8 && wv == 0) {
    const int row = g8 + glb;
    const float4* hrow = (const float4*)(hws + (size_t)row * H_);
    const float4 a0 = hrow[lane];
    const float4 a1 = hrow[lane + 64];
    float4* op = (float4*)(out + ((size_t)row * T_ + (T_ - 1)) * H_);
    op[lane]      = a0;
    op[lane + 64] = a1;
  }
}

extern "C" void kernel_launch(void* const* d_in, const int* in_sizes, int n_in,
                              void* d_out, int out_size, void* d_ws, size_t ws_size,
                              hipStream_t stream) {
  const float* x    = (const float*)d_in[0];
  const float* ts   = (const float*)d_in[1];
  const float* h0   = (const float*)d_in[2];
  const float* s0   = (const float*)d_in[3];
  const float* Wbb  = (const float*)d_in[4];
  const float* bbb  = (const float*)d_in[5];
  const float* Wff1 = (const float*)d_in[6];
  const float* bff1 = (const float*)d_in[7];
  const float* Wff2 = (const float*)d_in[8];
  const float* bff2 = (const float*)d_in[9];
  const float* Wta  = (const float*)d_in[10];
  const float* bta  = (const float*)d_in[11];
  const float* Wtb  = (const float*)d_in[12];
  const float* btb  = (const float*)d_in[13];
  float* out = (float*)d_out;

  // ws layout: [0,16384): 8 x 2KB group barrier regions; then h (128 KB); then bb (128 KB).
  unsigned* bar = (unsigned*)d_ws;
  float* hws  = (float*)((char*)d_ws + 16384);
  float* bbws = hws + B_ * H_;

  hipMemsetAsync(d_ws, 0, 16384, stream);

  void* args[] = {
      (void*)&x, (void*)&ts, (void*)&h0, (void*)&s0,
      (void*)&Wbb, (void*)&bbb, (void*)&Wff1, (void*)&bff1,
      (void*)&Wff2, (void*)&bff2, (void*)&Wta, (void*)&bta,
      (void*)&Wtb, (void*)&btb, (void*)&out, (void*)&hws,
      (void*)&bbws, (void*)&bar};

  hipLaunchCooperativeKernel((const void*)cfc_kernel, dim3(GRID_), dim3(NT_),
                             args, 0, stream);
}